// Round 8
// baseline (773.161 us; speedup 1.0000x reference)
//
#include <hip/hip_runtime.h>

// ---------------------------------------------------------------------------
// 2-layer GAT, edge-parallel (correctness first), input-dtype adaptive.
// Dropout = modern JAX default: x64 OFF + threefry_partitionable ON:
//   per flat element i: (o0,o1) = threefry2x32(key=(0,42), (hi32(i), lo32(i)))
//   bits = o0 ^ o1                      (32-bit fold, partitionable path)
//   u    = bitcast_f32((bits >> 9) | 0x3f800000) - 1.0f
//   keep = u < 0.7f ;  x = keep ? x/0.7f : 0
// Everything else identical to rounds 4/5/6 (established baseline).
// (Round 7 was an infra failure; this resubmits the round-7 kernel.)
// ---------------------------------------------------------------------------

__device__ __forceinline__ unsigned rotl32(unsigned x, unsigned r) {
  return (x << r) | (x >> (32u - r));
}

// JAX threefry2x32, key (0,42); returns both outputs.
__device__ __forceinline__ void threefry2_0_42(unsigned c0, unsigned c1,
                                               unsigned* o0, unsigned* o1) {
  const unsigned k0 = 0u, k1 = 42u;
  const unsigned k2 = k0 ^ k1 ^ 0x1BD11BDAu;
  unsigned ks[3] = {k0, k1, k2};
  unsigned x0 = c0 + ks[0];
  unsigned x1 = c1 + ks[1];
  const unsigned R[2][4] = {{13u, 15u, 26u, 6u}, {17u, 29u, 16u, 24u}};
#pragma unroll
  for (int i = 0; i < 5; ++i) {
#pragma unroll
    for (int j = 0; j < 4; ++j) {
      unsigned r = R[i & 1][j];
      x0 += x1;
      x1 = rotl32(x1, r);
      x1 ^= x0;
    }
    x0 += ks[(i + 1) % 3];
    x1 += ks[(i + 2) % 3] + (unsigned)(i + 1);
  }
  *o0 = x0;
  *o1 = x1;
}

__device__ __forceinline__ float ldf(const void* p, int isbf, size_t i) {
  if (isbf) {
    unsigned short u = ((const unsigned short*)p)[i];
    return __uint_as_float(((unsigned)u) << 16);
  }
  return ((const float*)p)[i];
}

__device__ __forceinline__ unsigned encf(float x) {
  unsigned b = __float_as_uint(x);
  return (b & 0x80000000u) ? ~b : (b | 0x80000000u);
}
__device__ __forceinline__ float decf(unsigned u) {
  unsigned b = (u & 0x80000000u) ? (u & 0x7fffffffu) : ~u;
  return __uint_as_float(b);
}

__global__ void k_detect(const void* __restrict__ A, const void* __restrict__ E,
                         int nNodes, int* flags) {
  int t = threadIdx.x;
  __shared__ int s_ok64, s_bfhits;
  if (t == 0) { s_ok64 = 1; s_bfhits = 0; }
  __syncthreads();
  long long v = ((const long long*)A)[t];
  if (!(v >= 0 && v < (long long)nNodes)) atomicAnd(&s_ok64, 0);
  unsigned w = ((const unsigned*)E)[t];
  unsigned b = (w >> 8) & 0x7F;
  if (b >= 0x3A && b <= 0x43) atomicAdd(&s_bfhits, 1);
  __syncthreads();
  if (t == 0) {
    flags[0] = s_ok64;
    flags[1] = (s_bfhits >= 200) ? 1 : 0;
  }
}

// [0]=W1(4096) [4096]=as1 [4160]=ad1 [4224]=b1 [4288]=W2 [8384]=as2
// [8448]=ad2 [8512]=b2 ; total 8576 floats
__global__ __launch_bounds__(256) void k_convert_small(
    const void* W1, const void* as1, const void* ad1, const void* b1,
    const void* W2, const void* as2, const void* ad2, const void* b2,
    const int* __restrict__ flags, float* __restrict__ outp) {
  int i = blockIdx.x * 256 + threadIdx.x;
  if (i >= 8576) return;
  int isbf = flags[1];
  float v;
  if (i < 4096) v = ldf(W1, isbf, i);
  else if (i < 4160) v = ldf(as1, isbf, i - 4096);
  else if (i < 4224) v = ldf(ad1, isbf, i - 4160);
  else if (i < 4288) v = ldf(b1, isbf, i - 4224);
  else if (i < 8384) v = ldf(W2, isbf, i - 4288);
  else if (i < 8448) v = ldf(as2, isbf, i - 8384);
  else if (i < 8512) v = ldf(ad2, isbf, i - 8448);
  else v = ldf(b2, isbf, i - 8512);
  outp[i] = v;
}

__device__ __forceinline__ void edge_sd(const void* __restrict__ A, int is64,
                                        int Eb, int e, int* s, int* d) {
  if (e < Eb) {
    if (is64) {
      *s = (int)((const long long*)A)[e];
      *d = (int)((const long long*)A)[(long long)Eb + e];
    } else {
      *s = ((const int*)A)[e];
      *d = ((const int*)A)[Eb + e];
    }
  } else {
    *s = *d = e - Eb;
  }
}

__global__ __launch_bounds__(256) void k_gemm_simple(const void* __restrict__ X,
                                                     const int* __restrict__ flags,
                                                     int xDetect,
                                                     const float* __restrict__ W,
                                                     float* __restrict__ H,
                                                     int total) {
  int i = blockIdx.x * 256 + threadIdx.x;
  if (i >= total) return;
  int isbf = xDetect ? flags[1] : 0;
  int row = i >> 6, j = i & 63;
  size_t base = (size_t)row * 64;
  float acc = 0.f;
#pragma unroll 8
  for (int k = 0; k < 64; ++k) acc = fmaf(ldf(X, isbf, base + k), W[k * 64 + j], acc);
  H[i] = acc;
}

__global__ __launch_bounds__(256) void k_scores(const float* __restrict__ H,
                                                const float* __restrict__ a_src,
                                                const float* __restrict__ a_dst,
                                                float* __restrict__ ssrc,
                                                float* __restrict__ sdst, int n) {
  int wid = (blockIdx.x * 256 + threadIdx.x) >> 6;
  int lane = threadIdx.x & 63;
  if (wid >= n) return;
  float hv = H[(size_t)wid * 64 + lane];
  float vs = hv * a_src[lane];
  float vd = hv * a_dst[lane];
#pragma unroll
  for (int d = 32; d; d >>= 1) {
    vs += __shfl_xor(vs, d);
    vd += __shfl_xor(vd, d);
  }
  if (lane == 0) {
    ssrc[wid] = vs;
    sdst[wid] = vd;
  }
}

__global__ __launch_bounds__(256) void k_clear(unsigned* __restrict__ amax,
                                               float* __restrict__ denom,
                                               float* __restrict__ acc, int n,
                                               int accTotal) {
  int stride = gridDim.x * 256;
  for (int i = blockIdx.x * 256 + threadIdx.x; i < accTotal; i += stride)
    acc[i] = 0.f;
  for (int i = blockIdx.x * 256 + threadIdx.x; i < n; i += stride) {
    amax[i] = 0u;
    denom[i] = 0.f;
  }
}

__global__ __launch_bounds__(256) void k_alpha(const void* __restrict__ A,
                                               const int* __restrict__ flags,
                                               const float* __restrict__ ssrc,
                                               const float* __restrict__ sdst,
                                               float* __restrict__ alpha,
                                               unsigned* __restrict__ amax,
                                               int Eb, int N) {
  int e = blockIdx.x * 256 + threadIdx.x;
  if (e >= Eb + N) return;
  int s, d;
  edge_sd(A, flags[0], Eb, e, &s, &d);
  float v = ssrc[s] + sdst[d];
  v = (v > 0.f) ? v : 0.2f * v;
  alpha[e] = v;
  atomicMax(&amax[d], encf(v));
}

__global__ __launch_bounds__(256) void k_expsum(const void* __restrict__ A,
                                                const int* __restrict__ flags,
                                                const float* __restrict__ alpha,
                                                const unsigned* __restrict__ amax,
                                                float* __restrict__ denom,
                                                int Eb, int N) {
  int e = blockIdx.x * 256 + threadIdx.x;
  if (e >= Eb + N) return;
  int s, d;
  edge_sd(A, flags[0], Eb, e, &s, &d);
  float ev = __expf(alpha[e] - decf(amax[d]));
  atomicAdd(&denom[d], ev);
}

__global__ __launch_bounds__(256) void k_scatter(const void* __restrict__ A,
                                                 const int* __restrict__ flags,
                                                 const float* __restrict__ alpha,
                                                 const unsigned* __restrict__ amax,
                                                 const float* __restrict__ denom,
                                                 const float* __restrict__ H,
                                                 float* __restrict__ acc,
                                                 int Eb, int N) {
  int wid = (blockIdx.x * 256 + threadIdx.x) >> 6;
  int lane = threadIdx.x & 63;
  if (wid >= Eb + N) return;
  int s, d;
  edge_sd(A, flags[0], Eb, wid, &s, &d);
  float coef = __expf(alpha[wid] - decf(amax[d])) / denom[d];
  atomicAdd(&acc[(size_t)d * 64 + lane], coef * H[(size_t)s * 64 + lane]);
}

// out[i] = relu(acc[i]+b); DROPOUT = partitionable-32 threefry bernoulli.
template <int DROPOUT>
__global__ __launch_bounds__(256) void k_epilogue(const float* __restrict__ acc,
                                                  const float* __restrict__ bias,
                                                  float* __restrict__ out,
                                                  int total) {
  int i = blockIdx.x * 256 + threadIdx.x;
  if (i >= total) return;
  float v = acc[i] + bias[i & 63];
  v = fmaxf(v, 0.f);
  if (DROPOUT) {
    // partitionable: counter = uint64(i) -> (c0,c1) = (0, i); 32-bit fold XOR
    unsigned o0, o1;
    threefry2_0_42(0u, (unsigned)i, &o0, &o1);
    unsigned bits = o0 ^ o1;
    float u = __uint_as_float((bits >> 9) | 0x3f800000u) - 1.0f;
    v = (u < 0.7f) ? (v / 0.7f) : 0.f;
  }
  out[i] = v;
}

extern "C" void kernel_launch(void* const* d_in, const int* in_sizes, int n_in,
                              void* d_out, int out_size, void* d_ws, size_t ws_size,
                              hipStream_t stream) {
  const void* E = d_in[0];
  const void* A = d_in[1];
  const void* W1 = d_in[2];
  const void* as1 = d_in[3];
  const void* ad1 = d_in[4];
  const void* b1 = d_in[5];
  const void* W2 = d_in[6];
  const void* as2 = d_in[7];
  const void* ad2 = d_in[8];
  const void* b2 = d_in[9];
  float* out = (float*)d_out;

  const int N = in_sizes[0] / 64;   // 50000
  const int Eb = in_sizes[1] / 2;   // 800000
  const int Etot = Eb + N;
  const int total = N * 64;         // 3,200,000

  float* ws = (float*)d_ws;
  float* h = ws;
  float* xacc = h + (size_t)total;
  float* ssrc = xacc + (size_t)total;
  float* sdst = ssrc + N;
  unsigned* amax = (unsigned*)(sdst + N);
  float* denom = (float*)(amax + N);
  float* alpha = denom + N;
  float* smallc = alpha + Etot;
  int* flags = (int*)(smallc + 8576);

  float* W1c = smallc;
  float* as1c = smallc + 4096;
  float* ad1c = smallc + 4160;
  float* b1c = smallc + 4224;
  float* W2c = smallc + 4288;
  float* as2c = smallc + 8384;
  float* ad2c = smallc + 8448;
  float* b2c = smallc + 8512;

  const int gElem = (total + 255) / 256;
  const int gEdge = (Etot + 255) / 256;
  const int gEdgeWave = (Etot + 3) / 4;
  const int gNodeBlocks = (N + 3) / 4;
  const int gClear = 2048;

  k_detect<<<1, 256, 0, stream>>>(A, E, N, flags);
  k_convert_small<<<(8576 + 255) / 256, 256, 0, stream>>>(
      W1, as1, ad1, b1, W2, as2, ad2, b2, flags, smallc);

  // ---- layer 1 ----
  k_gemm_simple<<<gElem, 256, 0, stream>>>(E, flags, 1, W1c, h, total);
  k_scores<<<gNodeBlocks, 256, 0, stream>>>(h, as1c, ad1c, ssrc, sdst, N);
  k_clear<<<gClear, 256, 0, stream>>>(amax, denom, xacc, N, total);
  k_alpha<<<gEdge, 256, 0, stream>>>(A, flags, ssrc, sdst, alpha, amax, Eb, N);
  k_expsum<<<gEdge, 256, 0, stream>>>(A, flags, alpha, amax, denom, Eb, N);
  k_scatter<<<gEdgeWave, 256, 0, stream>>>(A, flags, alpha, amax, denom, h, xacc,
                                           Eb, N);
  k_epilogue<1><<<gElem, 256, 0, stream>>>(xacc, b1c, xacc, total);

  // ---- layer 2 ----
  k_gemm_simple<<<gElem, 256, 0, stream>>>(xacc, flags, 0, W2c, h, total);
  k_scores<<<gNodeBlocks, 256, 0, stream>>>(h, as2c, ad2c, ssrc, sdst, N);
  k_clear<<<gClear, 256, 0, stream>>>(amax, denom, xacc, N, total);
  k_alpha<<<gEdge, 256, 0, stream>>>(A, flags, ssrc, sdst, alpha, amax, Eb, N);
  k_expsum<<<gEdge, 256, 0, stream>>>(A, flags, alpha, amax, denom, Eb, N);
  k_scatter<<<gEdgeWave, 256, 0, stream>>>(A, flags, alpha, amax, denom, h, xacc,
                                           Eb, N);
  k_epilogue<0><<<gElem, 256, 0, stream>>>(xacc, b2c, out, total);
}

// Round 9
// 416.411 us; speedup vs baseline: 1.8567x; 1.8567x over previous
//
#include <hip/hip_runtime.h>

// ---------------------------------------------------------------------------
// 2-layer GAT (PyG GATConv semantics), MI355X. Verified semantics (r8):
//   A = int32 on device, floats = f32, output f32,
//   dropout = threefry-partitionable 32-bit: bits = x0^x1 of
//             threefry2x32(key=(0,42), ctr=(0,i)); u=(bits>>9)|0x3f800000;
//             keep = (bitcast_f32(u)-1.0f) < 0.7f.
// This round: CSR (by dst) + wave-per-node aggregation (no atomics in the
// hot path), online softmax with alpha cached to a sequential buffer,
// LDS+shfl GEMM. Dropout fused into layer-1 aggregate epilogue.
// ---------------------------------------------------------------------------

__device__ __forceinline__ unsigned rotl32(unsigned x, unsigned r) {
  return (x << r) | (x >> (32u - r));
}

__device__ __forceinline__ void threefry2_0_42(unsigned c0, unsigned c1,
                                               unsigned* o0, unsigned* o1) {
  const unsigned k0 = 0u, k1 = 42u;
  const unsigned k2 = k0 ^ k1 ^ 0x1BD11BDAu;
  unsigned ks[3] = {k0, k1, k2};
  unsigned x0 = c0 + ks[0];
  unsigned x1 = c1 + ks[1];
  const unsigned R[2][4] = {{13u, 15u, 26u, 6u}, {17u, 29u, 16u, 24u}};
#pragma unroll
  for (int i = 0; i < 5; ++i) {
#pragma unroll
    for (int j = 0; j < 4; ++j) {
      unsigned r = R[i & 1][j];
      x0 += x1;
      x1 = rotl32(x1, r);
      x1 ^= x0;
    }
    x0 += ks[(i + 1) % 3];
    x1 += ks[(i + 2) % 3] + (unsigned)(i + 1);
  }
  *o0 = x0;
  *o1 = x1;
}

__device__ __forceinline__ float ldf(const void* p, int isbf, size_t i) {
  if (isbf) {
    unsigned short u = ((const unsigned short*)p)[i];
    return __uint_as_float(((unsigned)u) << 16);
  }
  return ((const float*)p)[i];
}

__global__ void k_detect(const void* __restrict__ A, const void* __restrict__ E,
                         int nNodes, int* flags) {
  int t = threadIdx.x;
  __shared__ int s_ok64, s_bfhits;
  if (t == 0) { s_ok64 = 1; s_bfhits = 0; }
  __syncthreads();
  long long v = ((const long long*)A)[t];
  if (!(v >= 0 && v < (long long)nNodes)) atomicAnd(&s_ok64, 0);
  unsigned w = ((const unsigned*)E)[t];
  unsigned b = (w >> 8) & 0x7F;
  if (b >= 0x3A && b <= 0x43) atomicAdd(&s_bfhits, 1);
  __syncthreads();
  if (t == 0) {
    flags[0] = s_ok64;
    flags[1] = (s_bfhits >= 200) ? 1 : 0;
  }
}

// [0]=W1(4096) [4096]=as1 [4160]=ad1 [4224]=b1 [4288]=W2 [8384]=as2
// [8448]=ad2 [8512]=b2 ; total 8576 floats
__global__ __launch_bounds__(256) void k_convert_small(
    const void* W1, const void* as1, const void* ad1, const void* b1,
    const void* W2, const void* as2, const void* ad2, const void* b2,
    const int* __restrict__ flags, float* __restrict__ outp) {
  int i = blockIdx.x * 256 + threadIdx.x;
  if (i >= 8576) return;
  int isbf = flags[1];
  float v;
  if (i < 4096) v = ldf(W1, isbf, i);
  else if (i < 4160) v = ldf(as1, isbf, i - 4096);
  else if (i < 4224) v = ldf(ad1, isbf, i - 4160);
  else if (i < 4288) v = ldf(b1, isbf, i - 4224);
  else if (i < 8384) v = ldf(W2, isbf, i - 4288);
  else if (i < 8448) v = ldf(as2, isbf, i - 8384);
  else if (i < 8512) v = ldf(ad2, isbf, i - 8448);
  else v = ldf(b2, isbf, i - 8512);
  outp[i] = v;
}

__device__ __forceinline__ void edge_sd(const void* __restrict__ A, int is64,
                                        int Eb, int e, int* s, int* d) {
  if (e < Eb) {
    if (is64) {
      *s = (int)((const long long*)A)[e];
      *d = (int)((const long long*)A)[(long long)Eb + e];
    } else {
      *s = ((const int*)A)[e];
      *d = ((const int*)A)[Eb + e];
    }
  } else {
    *s = *d = e - Eb;  // appended self-loop
  }
}

// h = X @ W (64x64) + row score dots. One wave per row, W staged in LDS.
__global__ __launch_bounds__(256) void k_gemm64(
    const void* __restrict__ X, const int* __restrict__ flags, int xDetect,
    const float* __restrict__ W, const float* __restrict__ a_src,
    const float* __restrict__ a_dst, float* __restrict__ H,
    float* __restrict__ ssrc, float* __restrict__ sdst, int n) {
  __shared__ float Wl[64 * 64];
  int t = threadIdx.x;
  for (int i = t; i < 64 * 64; i += 256) Wl[i] = W[i];
  __syncthreads();
  int lane = t & 63;
  int row = blockIdx.x * 4 + (t >> 6);
  if (row >= n) return;
  int isbf = xDetect ? flags[1] : 0;
  float xv = ldf(X, isbf, (size_t)row * 64 + lane);  // lane j holds X[row][j]
  float acc = 0.f;
#pragma unroll
  for (int k = 0; k < 64; ++k) {
    float xk = __shfl(xv, k);
    acc = fmaf(xk, Wl[k * 64 + lane], acc);
  }
  H[(size_t)row * 64 + lane] = acc;
  float vs = acc * a_src[lane];
  float vd = acc * a_dst[lane];
#pragma unroll
  for (int d = 32; d; d >>= 1) {
    vs += __shfl_xor(vs, d);
    vd += __shfl_xor(vd, d);
  }
  if (lane == 0) {
    ssrc[row] = vs;
    sdst[row] = vd;
  }
}

// ---- CSR build (by destination), runs once, reused by both layers ----
__global__ __launch_bounds__(256) void k_init(int* deg, int* cursor, int n) {
  int i = blockIdx.x * 256 + threadIdx.x;
  if (i < n) {
    deg[i] = 1;  // self-loop
    cursor[i] = 0;
  }
}

__global__ __launch_bounds__(256) void k_count(const void* __restrict__ A,
                                               const int* __restrict__ flags,
                                               int* deg, int Eb) {
  int e = blockIdx.x * 256 + threadIdx.x;
  if (e >= Eb) return;
  int d = flags[0] ? (int)((const long long*)A)[(long long)Eb + e]
                   : ((const int*)A)[Eb + e];
  atomicAdd(&deg[d], 1);
}

__global__ __launch_bounds__(1024) void k_scan_block(const int* __restrict__ deg,
                                                     int* __restrict__ incl,
                                                     int* __restrict__ blockSums,
                                                     int n) {
  __shared__ int sm[1024];
  int t = threadIdx.x;
  int g = blockIdx.x * 1024 + t;
  sm[t] = (g < n) ? deg[g] : 0;
  __syncthreads();
#pragma unroll
  for (int s = 1; s < 1024; s <<= 1) {
    int add = (t >= s) ? sm[t - s] : 0;
    __syncthreads();
    sm[t] += add;
    __syncthreads();
  }
  if (g < n) incl[g] = sm[t];
  if (t == 1023) blockSums[blockIdx.x] = sm[1023];
}

__global__ void k_scan_top(int* blockSums, int nb) {
  if (threadIdx.x == 0) {
    int run = 0;
    for (int b = 0; b < nb; ++b) {
      int v = blockSums[b];
      blockSums[b] = run;
      run += v;
    }
  }
}

__global__ __launch_bounds__(256) void k_offsets(const int* __restrict__ incl,
                                                 const int* __restrict__ blockSums,
                                                 int* __restrict__ offsets, int n) {
  int i = blockIdx.x * 256 + threadIdx.x;
  if (i > n) return;
  offsets[i] = (i == 0) ? 0 : incl[i - 1] + blockSums[(i - 1) >> 10];
}

__global__ __launch_bounds__(256) void k_fill(const void* __restrict__ A,
                                              const int* __restrict__ flags,
                                              const int* __restrict__ offsets,
                                              int* cursor, int* __restrict__ csr,
                                              int Eb, int nnode) {
  int e = blockIdx.x * 256 + threadIdx.x;
  if (e >= Eb + nnode) return;
  int s, d;
  edge_sd(A, flags[0], Eb, e, &s, &d);
  int slot = atomicAdd(&cursor[d], 1);
  csr[offsets[d] + slot] = s;
}

// One wave per destination node: online softmax + register aggregation.
template <int DROPOUT>
__global__ __launch_bounds__(256) void k_aggregate(
    const float* __restrict__ h, const float* __restrict__ ssrc,
    const float* __restrict__ sdst, const float* __restrict__ bias,
    const int* __restrict__ offsets, const int* __restrict__ csr,
    float* __restrict__ alphaE, float* __restrict__ out, int n) {
  int wid = (blockIdx.x * 256 + threadIdx.x) >> 6;
  int lane = threadIdx.x & 63;
  if (wid >= n) return;
  int off = offsets[wid];
  int end = offsets[wid + 1];
  float sd = sdst[wid];

  // pass A: alpha + per-lane online (max, sum); alpha cached sequentially
  float m = -1e30f, s = 0.f;
  for (int e = off + lane; e < end; e += 64) {
    float v = ssrc[csr[e]] + sd;
    v = (v > 0.f) ? v : 0.2f * v;
    alphaE[e] = v;
    float mn = fmaxf(m, v);
    s = s * __expf(m - mn) + __expf(v - mn);
    m = mn;
  }
#pragma unroll
  for (int d = 32; d; d >>= 1) {
    float mo = __shfl_xor(m, d);
    float so = __shfl_xor(s, d);
    float mn = fmaxf(m, mo);
    s = s * __expf(m - mn) + so * __expf(mo - mn);
    m = mn;
  }
  float inv = 1.f / s;

  // pass B: out[j] = sum_e coef_e * h[src_e][j]  (lane j = feature j)
  float acc = 0.f;
  for (int base = off; base < end; base += 64) {
    int e = base + lane;
    float c = 0.f;
    int sl = 0;
    if (e < end) {
      c = __expf(alphaE[e] - m) * inv;
      sl = csr[e];
    }
    int cnt = min(64, end - base);
    for (int l = 0; l < cnt; ++l) {
      float cl = __shfl(c, l);
      int srow = __shfl(sl, l);
      acc = fmaf(cl, h[(size_t)srow * 64 + lane], acc);
    }
  }

  acc += bias[lane];
  acc = fmaxf(acc, 0.f);
  if (DROPOUT) {
    unsigned i = (unsigned)wid * 64u + (unsigned)lane;
    unsigned o0, o1;
    threefry2_0_42(0u, i, &o0, &o1);
    unsigned bits = o0 ^ o1;
    float u = __uint_as_float((bits >> 9) | 0x3f800000u) - 1.0f;
    acc = (u < 0.7f) ? (acc / 0.7f) : 0.f;
  }
  out[(size_t)wid * 64 + lane] = acc;
}

extern "C" void kernel_launch(void* const* d_in, const int* in_sizes, int n_in,
                              void* d_out, int out_size, void* d_ws, size_t ws_size,
                              hipStream_t stream) {
  const void* E = d_in[0];
  const void* A = d_in[1];
  const void* W1 = d_in[2];
  const void* as1 = d_in[3];
  const void* ad1 = d_in[4];
  const void* b1 = d_in[5];
  const void* W2 = d_in[6];
  const void* as2 = d_in[7];
  const void* ad2 = d_in[8];
  const void* b2 = d_in[9];
  float* out = (float*)d_out;

  const int N = in_sizes[0] / 64;   // 50000
  const int Eb = in_sizes[1] / 2;   // 800000
  const int Etot = Eb + N;          // 850000
  const int total = N * 64;         // 3,200,000

  // workspace (all 4B elements)
  float* ws = (float*)d_ws;
  float* h = ws;                           // total
  float* x1 = h + (size_t)total;           // total
  float* ssrc = x1 + (size_t)total;        // N
  float* sdst = ssrc + N;                  // N
  float* alphaE = sdst + N;                // Etot
  float* smallc = alphaE + Etot;           // 8576
  int* deg = (int*)(smallc + 8576);        // N
  int* incl = deg + N;                     // N
  int* offsets = incl + N;                 // N+1
  int* cursor = offsets + (N + 1);         // N
  int* blockSums = cursor + N;             // 256
  int* flags = blockSums + 256;            // 2
  int* csr = flags + 2;                    // Etot

  float* W1c = smallc;
  float* as1c = smallc + 4096;
  float* ad1c = smallc + 4160;
  float* b1c = smallc + 4224;
  float* W2c = smallc + 4288;
  float* as2c = smallc + 8384;
  float* ad2c = smallc + 8448;
  float* b2c = smallc + 8512;

  const int gNodeBlocks = (N + 3) / 4;          // 4 waves (rows) per block
  const int gEdge = (Etot + 255) / 256;
  const int nbScan = (N + 1023) / 1024;

  k_detect<<<1, 256, 0, stream>>>(A, E, N, flags);
  k_convert_small<<<(8576 + 255) / 256, 256, 0, stream>>>(
      W1, as1, ad1, b1, W2, as2, ad2, b2, flags, smallc);

  // CSR build (once)
  k_init<<<(N + 255) / 256, 256, 0, stream>>>(deg, cursor, N);
  k_count<<<(Eb + 255) / 256, 256, 0, stream>>>(A, flags, deg, Eb);
  k_scan_block<<<nbScan, 1024, 0, stream>>>(deg, incl, blockSums, N);
  k_scan_top<<<1, 64, 0, stream>>>(blockSums, nbScan);
  k_offsets<<<(N + 1 + 255) / 256, 256, 0, stream>>>(incl, blockSums, offsets, N);
  k_fill<<<gEdge, 256, 0, stream>>>(A, flags, offsets, cursor, csr, Eb, N);

  // ---- layer 1 ----
  k_gemm64<<<gNodeBlocks, 256, 0, stream>>>(E, flags, 1, W1c, as1c, ad1c, h,
                                            ssrc, sdst, N);
  k_aggregate<1><<<gNodeBlocks, 256, 0, stream>>>(h, ssrc, sdst, b1c, offsets,
                                                  csr, alphaE, x1, N);

  // ---- layer 2 ----
  k_gemm64<<<gNodeBlocks, 256, 0, stream>>>(x1, flags, 0, W2c, as2c, ad2c, h,
                                            ssrc, sdst, N);
  k_aggregate<0><<<gNodeBlocks, 256, 0, stream>>>(h, ssrc, sdst, b2c, offsets,
                                                  csr, alphaE, out, N);
}

// Round 10
// 396.354 us; speedup vs baseline: 1.9507x; 1.0506x over previous
//
#include <hip/hip_runtime.h>

// ---------------------------------------------------------------------------
// 2-layer GAT (PyG GATConv), MI355X. Verified semantics (r8/r9):
//   A=int32 on device, floats=f32, out=f32; dropout = threefry-partitionable
//   32-bit: bits = x0^x1 of threefry2x32(key=(0,42), ctr=(0,i)).
// r10: 7 dispatches (prep | count+gemm1 | scan1 | fill | agg1 | gemm2 | agg2),
// aggregate pass B = 4-edge x 16-lane float4 gather, register-resident alpha.
// ---------------------------------------------------------------------------

__device__ __forceinline__ unsigned rotl32(unsigned x, unsigned r) {
  return (x << r) | (x >> (32u - r));
}

__device__ __forceinline__ void threefry2_0_42(unsigned c0, unsigned c1,
                                               unsigned* o0, unsigned* o1) {
  const unsigned k0 = 0u, k1 = 42u;
  const unsigned k2 = k0 ^ k1 ^ 0x1BD11BDAu;
  unsigned ks[3] = {k0, k1, k2};
  unsigned x0 = c0 + ks[0];
  unsigned x1 = c1 + ks[1];
  const unsigned R[2][4] = {{13u, 15u, 26u, 6u}, {17u, 29u, 16u, 24u}};
#pragma unroll
  for (int i = 0; i < 5; ++i) {
#pragma unroll
    for (int j = 0; j < 4; ++j) {
      unsigned r = R[i & 1][j];
      x0 += x1;
      x1 = rotl32(x1, r);
      x1 ^= x0;
    }
    x0 += ks[(i + 1) % 3];
    x1 += ks[(i + 2) % 3] + (unsigned)(i + 1);
  }
  *o0 = x0;
  *o1 = x1;
}

__device__ __forceinline__ float ldf(const void* p, int isbf, size_t i) {
  if (isbf) {
    unsigned short u = ((const unsigned short*)p)[i];
    return __uint_as_float(((unsigned)u) << 16);
  }
  return ((const float*)p)[i];
}

// prep: per-block local dtype detection + small-tensor convert + deg/cursor
// init; block 0 publishes flags for later kernels.
__global__ __launch_bounds__(256) void k_prep(
    const void* __restrict__ A, const void* __restrict__ Ein, int nNodes,
    const void* W1, const void* as1, const void* ad1, const void* b1,
    const void* W2, const void* as2, const void* ad2, const void* b2,
    float* __restrict__ smallc, int* __restrict__ deg, int* __restrict__ cursor,
    int* __restrict__ flags) {
  __shared__ int s_ok64, s_bf;
  int t = threadIdx.x;
  if (t == 0) { s_ok64 = 1; s_bf = 0; }
  __syncthreads();
  long long v = ((const long long*)A)[t];
  if (!(v >= 0 && v < (long long)nNodes)) atomicAnd(&s_ok64, 0);
  unsigned w = ((const unsigned*)Ein)[t];
  unsigned b = (w >> 8) & 0x7F;
  if (b >= 0x3A && b <= 0x43) atomicAdd(&s_bf, 1);
  __syncthreads();
  int isbf = (s_bf >= 200) ? 1 : 0;
  int i = blockIdx.x * 256 + t;
  if (blockIdx.x == 0 && t == 0) {
    flags[0] = s_ok64;
    flags[1] = isbf;
  }
  if (i < 8576) {
    float x;
    if (i < 4096) x = ldf(W1, isbf, i);
    else if (i < 4160) x = ldf(as1, isbf, i - 4096);
    else if (i < 4224) x = ldf(ad1, isbf, i - 4160);
    else if (i < 4288) x = ldf(b1, isbf, i - 4224);
    else if (i < 8384) x = ldf(W2, isbf, i - 4288);
    else if (i < 8448) x = ldf(as2, isbf, i - 8384);
    else if (i < 8512) x = ldf(ad2, isbf, i - 8448);
    else x = ldf(b2, isbf, i - 8512);
    smallc[i] = x;
  }
  if (i < nNodes) {
    deg[i] = 1;  // self-loop
    cursor[i] = 0;
  }
}

// fused: blocks [0,nCountBlocks) count dst degrees; rest do layer-1 GEMM.
__global__ __launch_bounds__(256) void k_count_gemm(
    const void* __restrict__ A, const int* __restrict__ flags, int Eb,
    int* __restrict__ deg, const void* __restrict__ X,
    const float* __restrict__ W, const float* __restrict__ a_src,
    const float* __restrict__ a_dst, float* __restrict__ H,
    float* __restrict__ ssrc, float* __restrict__ sdst, int n,
    int nCountBlocks) {
  __shared__ float Wl[64 * 64];
  int t = threadIdx.x;
  if ((int)blockIdx.x < nCountBlocks) {
    int e = blockIdx.x * 256 + t;
    if (e < Eb) {
      int d = flags[0] ? (int)((const long long*)A)[(long long)Eb + e]
                       : ((const int*)A)[Eb + e];
      atomicAdd(&deg[d], 1);
    }
    return;
  }
  int bid = blockIdx.x - nCountBlocks;
  for (int i = t; i < 64 * 64; i += 256) Wl[i] = W[i];
  __syncthreads();
  int lane = t & 63;
  int row = bid * 4 + (t >> 6);
  if (row >= n) return;
  int isbf = flags[1];
  float xv = ldf(X, isbf, (size_t)row * 64 + lane);
  float acc = 0.f;
#pragma unroll
  for (int k = 0; k < 64; ++k) {
    float xk = __shfl(xv, k);
    acc = fmaf(xk, Wl[k * 64 + lane], acc);
  }
  H[(size_t)row * 64 + lane] = acc;
  float vs = acc * a_src[lane];
  float vd = acc * a_dst[lane];
#pragma unroll
  for (int d = 32; d; d >>= 1) {
    vs += __shfl_xor(vs, d);
    vd += __shfl_xor(vd, d);
  }
  if (lane == 0) {
    ssrc[row] = vs;
    sdst[row] = vd;
  }
}

// plain layer-2 GEMM (X = x1, f32)
__global__ __launch_bounds__(256) void k_gemm64(
    const float* __restrict__ X, const float* __restrict__ W,
    const float* __restrict__ a_src, const float* __restrict__ a_dst,
    float* __restrict__ H, float* __restrict__ ssrc, float* __restrict__ sdst,
    int n) {
  __shared__ float Wl[64 * 64];
  int t = threadIdx.x;
  for (int i = t; i < 64 * 64; i += 256) Wl[i] = W[i];
  __syncthreads();
  int lane = t & 63;
  int row = blockIdx.x * 4 + (t >> 6);
  if (row >= n) return;
  float xv = X[(size_t)row * 64 + lane];
  float acc = 0.f;
#pragma unroll
  for (int k = 0; k < 64; ++k) {
    float xk = __shfl(xv, k);
    acc = fmaf(xk, Wl[k * 64 + lane], acc);
  }
  H[(size_t)row * 64 + lane] = acc;
  float vs = acc * a_src[lane];
  float vd = acc * a_dst[lane];
#pragma unroll
  for (int d = 32; d; d >>= 1) {
    vs += __shfl_xor(vs, d);
    vd += __shfl_xor(vd, d);
  }
  if (lane == 0) {
    ssrc[row] = vs;
    sdst[row] = vd;
  }
}

// single-block chunked exclusive scan: deg[0..n) -> offsets[0..n]
__global__ __launch_bounds__(1024) void k_scan_one(const int* __restrict__ deg,
                                                   int* __restrict__ offsets,
                                                   int n, int etot) {
  __shared__ int wsum[16];
  __shared__ int carry;
  int t = threadIdx.x;
  int lane = t & 63;
  int w = t >> 6;
  if (t == 0) carry = 0;
  __syncthreads();
  for (int base = 0; base < n; base += 1024) {
    int i = base + t;
    int x = (i < n) ? deg[i] : 0;
    int sc = x;
#pragma unroll
    for (int d = 1; d < 64; d <<= 1) {
      int o = __shfl_up(sc, d);
      if (lane >= d) sc += o;
    }
    if (lane == 63) wsum[w] = sc;
    __syncthreads();
    int cbase = carry;
    if (t < 64) {
      int v = (t < 16) ? wsum[t] : 0;
#pragma unroll
      for (int d = 1; d < 16; d <<= 1) {
        int o = __shfl_up(v, d);
        if (lane >= d) v += o;
      }
      if (t < 16) wsum[t] = v;
    }
    __syncthreads();
    int wpre = (w == 0) ? 0 : wsum[w - 1];
    if (i < n) offsets[i] = cbase + wpre + (sc - x);
    int tot = wsum[15];
    __syncthreads();
    if (t == 0) carry = cbase + tot;
    __syncthreads();
  }
  if (t == 0) offsets[n] = etot;
}

__global__ __launch_bounds__(256) void k_fill(const void* __restrict__ A,
                                              const int* __restrict__ flags,
                                              const int* __restrict__ offsets,
                                              int* cursor, int* __restrict__ csr,
                                              int Eb, int nnode) {
  int e = blockIdx.x * 256 + threadIdx.x;
  if (e >= Eb + nnode) return;
  int s, d;
  if (e < Eb) {
    if (flags[0]) {
      s = (int)((const long long*)A)[e];
      d = (int)((const long long*)A)[(long long)Eb + e];
    } else {
      s = ((const int*)A)[e];
      d = ((const int*)A)[Eb + e];
    }
  } else {
    s = d = e - Eb;
  }
  int slot = atomicAdd(&cursor[d], 1);
  csr[offsets[d] + slot] = s;
}

#define AGG_STEP(IDX, ACC)                                              \
  {                                                                     \
    int idx_ = (IDX);                                                   \
    float cl_ = __shfl(c, idx_);                                        \
    int sr_ = __shfl(sl, idx_);                                         \
    if (idx_ < glim) {                                                  \
      const float4 hv_ = *(const float4*)&h[(size_t)sr_ * 64 + f4 * 4]; \
      ACC.x = fmaf(cl_, hv_.x, ACC.x);                                  \
      ACC.y = fmaf(cl_, hv_.y, ACC.y);                                  \
      ACC.z = fmaf(cl_, hv_.z, ACC.z);                                  \
      ACC.w = fmaf(cl_, hv_.w, ACC.w);                                  \
    }                                                                   \
  }

// wave-per-node aggregate: register alpha (deg<=64 fast path), pass B as
// 4-edge x 16-lane float4 gather with dual accumulators.
template <int DROPOUT>
__global__ __launch_bounds__(256) void k_aggregate(
    const float* __restrict__ h, const float* __restrict__ ssrc,
    const float* __restrict__ sdst, const float* __restrict__ bias,
    const int* __restrict__ offsets, const int* __restrict__ csr,
    float* __restrict__ alphaE, float* __restrict__ out, int n) {
  int wid = (blockIdx.x * 256 + threadIdx.x) >> 6;
  int lane = threadIdx.x & 63;
  if (wid >= n) return;
  int off = offsets[wid];
  int end = offsets[wid + 1];
  int g = end - off;
  float sd = sdst[wid];
  int e4 = lane >> 4, f4 = lane & 15;
  float4 acc0 = {0.f, 0.f, 0.f, 0.f}, acc1 = {0.f, 0.f, 0.f, 0.f};

  if (g <= 64) {
    int sl = 0;
    float v = -1e30f;
    if (lane < g) {
      sl = csr[off + lane];
      float tv = ssrc[sl] + sd;
      v = (tv > 0.f) ? tv : 0.2f * tv;
    }
    float m = v;
#pragma unroll
    for (int d = 32; d; d >>= 1) m = fmaxf(m, __shfl_xor(m, d));
    float ex = (lane < g) ? __expf(v - m) : 0.f;
    float s = ex;
#pragma unroll
    for (int d = 32; d; d >>= 1) s += __shfl_xor(s, d);
    float c = ex * (1.f / s);
    int glim = g;
    for (int cb = 0; cb < g; cb += 8) {
      AGG_STEP(cb + e4, acc0)
      AGG_STEP(cb + 4 + e4, acc1)
    }
  } else {
    // slow path (deg > 64): online softmax with alphaE spill
    float mm = -1e30f, ss = 0.f;
    for (int e = off + lane; e < end; e += 64) {
      int sl2 = csr[e];
      float tv = ssrc[sl2] + sd;
      tv = (tv > 0.f) ? tv : 0.2f * tv;
      alphaE[e] = tv;
      float mn = fmaxf(mm, tv);
      ss = ss * __expf(mm - mn) + __expf(tv - mn);
      mm = mn;
    }
#pragma unroll
    for (int d = 32; d; d >>= 1) {
      float mo = __shfl_xor(mm, d);
      float so = __shfl_xor(ss, d);
      float mn = fmaxf(mm, mo);
      ss = ss * __expf(mm - mn) + so * __expf(mo - mn);
      mm = mn;
    }
    float inv = 1.f / ss;
    for (int base = off; base < end; base += 64) {
      int e = base + lane;
      int cnt = min(64, end - base);
      float c = 0.f;
      int sl = 0;
      if (e < end) {
        c = __expf(alphaE[e] - mm) * inv;
        sl = csr[e];
      }
      int glim = cnt;
      for (int cb = 0; cb < cnt; cb += 8) {
        AGG_STEP(cb + e4, acc0)
        AGG_STEP(cb + 4 + e4, acc1)
      }
    }
  }

  float4 r;
  r.x = acc0.x + acc1.x;
  r.y = acc0.y + acc1.y;
  r.z = acc0.z + acc1.z;
  r.w = acc0.w + acc1.w;
#pragma unroll
  for (int d = 16; d < 64; d <<= 1) {
    r.x += __shfl_xor(r.x, d);
    r.y += __shfl_xor(r.y, d);
    r.z += __shfl_xor(r.z, d);
    r.w += __shfl_xor(r.w, d);
  }

  unsigned long long mask = 0ull;
  if (DROPOUT) {
    unsigned i0 = (unsigned)wid * 64u + (unsigned)lane;
    unsigned o0, o1;
    threefry2_0_42(0u, i0, &o0, &o1);
    unsigned bits = o0 ^ o1;
    float u = __uint_as_float((bits >> 9) | 0x3f800000u) - 1.0f;
    mask = __ballot(u < 0.7f);
  }

  if (lane < 16) {
    const float4 b4 = *(const float4*)&bias[lane * 4];
    r.x = fmaxf(r.x + b4.x, 0.f);
    r.y = fmaxf(r.y + b4.y, 0.f);
    r.z = fmaxf(r.z + b4.z, 0.f);
    r.w = fmaxf(r.w + b4.w, 0.f);
    if (DROPOUT) {
      r.x = ((mask >> (lane * 4 + 0)) & 1ull) ? r.x / 0.7f : 0.f;
      r.y = ((mask >> (lane * 4 + 1)) & 1ull) ? r.y / 0.7f : 0.f;
      r.z = ((mask >> (lane * 4 + 2)) & 1ull) ? r.z / 0.7f : 0.f;
      r.w = ((mask >> (lane * 4 + 3)) & 1ull) ? r.w / 0.7f : 0.f;
    }
    *(float4*)&out[(size_t)wid * 64 + lane * 4] = r;
  }
}

extern "C" void kernel_launch(void* const* d_in, const int* in_sizes, int n_in,
                              void* d_out, int out_size, void* d_ws, size_t ws_size,
                              hipStream_t stream) {
  const void* E = d_in[0];
  const void* A = d_in[1];
  const void* W1 = d_in[2];
  const void* as1 = d_in[3];
  const void* ad1 = d_in[4];
  const void* b1 = d_in[5];
  const void* W2 = d_in[6];
  const void* as2 = d_in[7];
  const void* ad2 = d_in[8];
  const void* b2 = d_in[9];
  float* out = (float*)d_out;

  const int N = in_sizes[0] / 64;   // 50000
  const int Eb = in_sizes[1] / 2;   // 800000
  const int Etot = Eb + N;          // 850000
  const int total = N * 64;

  float* ws = (float*)d_ws;
  float* h = ws;                          // total
  float* x1 = h + (size_t)total;          // total
  float* ssrc = x1 + (size_t)total;       // N
  float* sdst = ssrc + N;                 // N
  float* alphaE = sdst + N;               // Etot
  float* smallc = alphaE + Etot;          // 8576
  int* deg = (int*)(smallc + 8576);       // N
  int* offsets = deg + N;                 // N+1
  int* cursor = offsets + (N + 1);        // N
  int* flags = cursor + N;                // 2
  int* csr = flags + 2;                   // Etot

  float* W1c = smallc;
  float* as1c = smallc + 4096;
  float* ad1c = smallc + 4160;
  float* b1c = smallc + 4224;
  float* W2c = smallc + 4288;
  float* as2c = smallc + 8384;
  float* ad2c = smallc + 8448;
  float* b2c = smallc + 8512;

  const int gPrep = (N + 255) / 256;            // 196 (covers 8576 too)
  const int nCountBlocks = (Eb + 255) / 256;    // 3125
  const int gGemm = (N + 3) / 4;                // 12500
  const int gFill = (Etot + 255) / 256;         // 3321

  k_prep<<<gPrep, 256, 0, stream>>>(A, E, N, W1, as1, ad1, b1, W2, as2, ad2,
                                    b2, smallc, deg, cursor, flags);
  k_count_gemm<<<nCountBlocks + gGemm, 256, 0, stream>>>(
      A, flags, Eb, deg, E, W1c, as1c, ad1c, h, ssrc, sdst, N, nCountBlocks);
  k_scan_one<<<1, 1024, 0, stream>>>(deg, offsets, N, Etot);
  k_fill<<<gFill, 256, 0, stream>>>(A, flags, offsets, cursor, csr, Eb, N);
  k_aggregate<1><<<gGemm, 256, 0, stream>>>(h, ssrc, sdst, b1c, offsets, csr,
                                            alphaE, x1, N);
  k_gemm64<<<gGemm, 256, 0, stream>>>(x1, W2c, as2c, ad2c, h, ssrc, sdst, N);
  k_aggregate<0><<<gGemm, 256, 0, stream>>>(h, ssrc, sdst, b2c, offsets, csr,
                                            alphaE, out, N);
}

// Round 11
// 320.519 us; speedup vs baseline: 2.4122x; 1.2366x over previous
//
#include <hip/hip_runtime.h>

// ---------------------------------------------------------------------------
// 2-layer GAT (PyG GATConv), MI355X. Verified semantics (r8-r10):
//   A=int32 on device, floats=f32, out=f32; dropout = threefry-partitionable
//   32-bit: bits = x0^x1 of threefry2x32(key=(0,42), ctr=(0,i)).
// r11: register-tiled GEMM (64x64 tile, 4x4/thread, Xt transposed in LDS,
// ds_read_b128 feeds, 8:1 FMA:DS) replacing the DS-bound shfl GEMM.
// 7 dispatches: prep | count+gemm1 | scan | fill | agg1 | gemm2 | agg2.
// ---------------------------------------------------------------------------

#define XT_STRIDE 68  // 16B-aligned b128 reads (68*4=272=17*16), 2-way banks

__device__ __forceinline__ unsigned rotl32(unsigned x, unsigned r) {
  return (x << r) | (x >> (32u - r));
}

__device__ __forceinline__ void threefry2_0_42(unsigned c0, unsigned c1,
                                               unsigned* o0, unsigned* o1) {
  const unsigned k0 = 0u, k1 = 42u;
  const unsigned k2 = k0 ^ k1 ^ 0x1BD11BDAu;
  unsigned ks[3] = {k0, k1, k2};
  unsigned x0 = c0 + ks[0];
  unsigned x1 = c1 + ks[1];
  const unsigned R[2][4] = {{13u, 15u, 26u, 6u}, {17u, 29u, 16u, 24u}};
#pragma unroll
  for (int i = 0; i < 5; ++i) {
#pragma unroll
    for (int j = 0; j < 4; ++j) {
      unsigned r = R[i & 1][j];
      x0 += x1;
      x1 = rotl32(x1, r);
      x1 ^= x0;
    }
    x0 += ks[(i + 1) % 3];
    x1 += ks[(i + 2) % 3] + (unsigned)(i + 1);
  }
  *o0 = x0;
  *o1 = x1;
}

__device__ __forceinline__ float ldf(const void* p, int isbf, size_t i) {
  if (isbf) {
    unsigned short u = ((const unsigned short*)p)[i];
    return __uint_as_float(((unsigned)u) << 16);
  }
  return ((const float*)p)[i];
}

// prep: dtype detect (block-local) + small-tensor convert + deg/cursor init.
__global__ __launch_bounds__(256) void k_prep(
    const void* __restrict__ A, const void* __restrict__ Ein, int nNodes,
    const void* W1, const void* as1, const void* ad1, const void* b1,
    const void* W2, const void* as2, const void* ad2, const void* b2,
    float* __restrict__ smallc, int* __restrict__ deg, int* __restrict__ cursor,
    int* __restrict__ flags) {
  __shared__ int s_ok64, s_bf;
  int t = threadIdx.x;
  if (t == 0) { s_ok64 = 1; s_bf = 0; }
  __syncthreads();
  long long v = ((const long long*)A)[t];
  if (!(v >= 0 && v < (long long)nNodes)) atomicAnd(&s_ok64, 0);
  unsigned w = ((const unsigned*)Ein)[t];
  unsigned b = (w >> 8) & 0x7F;
  if (b >= 0x3A && b <= 0x43) atomicAdd(&s_bf, 1);
  __syncthreads();
  int isbf = (s_bf >= 200) ? 1 : 0;
  int i = blockIdx.x * 256 + t;
  if (blockIdx.x == 0 && t == 0) {
    flags[0] = s_ok64;
    flags[1] = isbf;
  }
  if (i < 8576) {
    float x;
    if (i < 4096) x = ldf(W1, isbf, i);
    else if (i < 4160) x = ldf(as1, isbf, i - 4096);
    else if (i < 4224) x = ldf(ad1, isbf, i - 4160);
    else if (i < 4288) x = ldf(b1, isbf, i - 4224);
    else if (i < 8384) x = ldf(W2, isbf, i - 4288);
    else if (i < 8448) x = ldf(as2, isbf, i - 8384);
    else if (i < 8512) x = ldf(ad2, isbf, i - 8448);
    else x = ldf(b2, isbf, i - 8512);
    smallc[i] = x;
  }
  if (i < nNodes) {
    deg[i] = 1;  // self-loop
    cursor[i] = 0;
  }
}

// fused: blocks [0,nCountBlocks) count dst degrees; rest: tiled GEMM.
// Tile: 64 rows x 64 cols per block; thread t owns rows 4*(t>>4)..+3 of the
// tile and cols 4*(t&15)..+3 (rows wave-local -> score reduce via shfl).
__global__ __launch_bounds__(256) void k_count_gemm(
    const void* __restrict__ A, const int* __restrict__ flags, int Eb,
    int* __restrict__ deg, const void* __restrict__ X, int xDetect,
    const float* __restrict__ W, const float* __restrict__ a_src,
    const float* __restrict__ a_dst, float* __restrict__ H,
    float* __restrict__ ssrc, float* __restrict__ sdst, int n,
    int nCountBlocks) {
  __shared__ float Xt[64 * XT_STRIDE];  // [k][row], transposed
  __shared__ float Ws[64 * 64];         // [k][j]
  int t = threadIdx.x;
  if ((int)blockIdx.x < nCountBlocks) {
    int e = blockIdx.x * 256 + t;
    if (e < Eb) {
      int d = flags[0] ? (int)((const long long*)A)[(long long)Eb + e]
                       : ((const int*)A)[Eb + e];
      atomicAdd(&deg[d], 1);
    }
    return;
  }
  int bid = blockIdx.x - nCountBlocks;
  int row0 = bid * 64;
  int isbf = xDetect ? flags[1] : 0;

  // stage W: coalesced float4 global read, aligned float4 LDS write
#pragma unroll
  for (int i = t; i < 1024; i += 256) {
    int k = i >> 4, jq = i & 15;
    *(float4*)&Ws[k * 64 + jq * 4] = *(const float4*)&W[k * 64 + jq * 4];
  }
  // stage X transposed: coalesced float4 read (4 rows x full k per instr)
#pragma unroll
  for (int i = t; i < 1024; i += 256) {
    int q = i & 15, r = i >> 4;
    int row = row0 + r;
    float4 v = {0.f, 0.f, 0.f, 0.f};
    if (row < n) {
      if (isbf) {
        v.x = ldf(X, 1, (size_t)row * 64 + q * 4 + 0);
        v.y = ldf(X, 1, (size_t)row * 64 + q * 4 + 1);
        v.z = ldf(X, 1, (size_t)row * 64 + q * 4 + 2);
        v.w = ldf(X, 1, (size_t)row * 64 + q * 4 + 3);
      } else {
        v = *(const float4*)&((const float*)X)[(size_t)row * 64 + q * 4];
      }
    }
    Xt[(q * 4 + 0) * XT_STRIDE + r] = v.x;
    Xt[(q * 4 + 1) * XT_STRIDE + r] = v.y;
    Xt[(q * 4 + 2) * XT_STRIDE + r] = v.z;
    Xt[(q * 4 + 3) * XT_STRIDE + r] = v.w;
  }
  __syncthreads();

  int r0 = (t >> 4) * 4;  // tile-row base (wave-local: 16 rows/wave)
  int c0 = (t & 15) * 4;  // tile-col base
  float acc[4][4];
#pragma unroll
  for (int r = 0; r < 4; ++r)
#pragma unroll
    for (int c = 0; c < 4; ++c) acc[r][c] = 0.f;

#pragma unroll 8
  for (int k = 0; k < 64; ++k) {
    float4 a4 = *(const float4*)&Xt[k * XT_STRIDE + r0];
    float4 b4 = *(const float4*)&Ws[k * 64 + c0];
    const float av[4] = {a4.x, a4.y, a4.z, a4.w};
    const float bv[4] = {b4.x, b4.y, b4.z, b4.w};
#pragma unroll
    for (int r = 0; r < 4; ++r)
#pragma unroll
      for (int c = 0; c < 4; ++c) acc[r][c] = fmaf(av[r], bv[c], acc[r][c]);
  }

  // scores: per-thread 4-col partials, reduce over the 16 col-groups (t&15)
  const float4 asr = *(const float4*)&a_src[c0];
  const float4 adr = *(const float4*)&a_dst[c0];
#pragma unroll
  for (int r = 0; r < 4; ++r) {
    float vs = acc[r][0] * asr.x + acc[r][1] * asr.y + acc[r][2] * asr.z +
               acc[r][3] * asr.w;
    float vd = acc[r][0] * adr.x + acc[r][1] * adr.y + acc[r][2] * adr.z +
               acc[r][3] * adr.w;
#pragma unroll
    for (int d = 1; d < 16; d <<= 1) {
      vs += __shfl_xor(vs, d);
      vd += __shfl_xor(vd, d);
    }
    int row = row0 + r0 + r;
    if ((t & 15) == 0 && row < n) {
      ssrc[row] = vs;
      sdst[row] = vd;
    }
  }

  // store h (coalesced float4: 4 rows x 256B per instr)
#pragma unroll
  for (int r = 0; r < 4; ++r) {
    int row = row0 + r0 + r;
    if (row < n) {
      float4 o = {acc[r][0], acc[r][1], acc[r][2], acc[r][3]};
      *(float4*)&H[(size_t)row * 64 + c0] = o;
    }
  }
}

// single-block chunked exclusive scan: deg[0..n) -> offsets[0..n]
__global__ __launch_bounds__(1024) void k_scan_one(const int* __restrict__ deg,
                                                   int* __restrict__ offsets,
                                                   int n, int etot) {
  __shared__ int wsum[16];
  __shared__ int carry;
  int t = threadIdx.x;
  int lane = t & 63;
  int w = t >> 6;
  if (t == 0) carry = 0;
  __syncthreads();
  for (int base = 0; base < n; base += 1024) {
    int i = base + t;
    int x = (i < n) ? deg[i] : 0;
    int sc = x;
#pragma unroll
    for (int d = 1; d < 64; d <<= 1) {
      int o = __shfl_up(sc, d);
      if (lane >= d) sc += o;
    }
    if (lane == 63) wsum[w] = sc;
    __syncthreads();
    int cbase = carry;
    if (t < 64) {
      int v = (t < 16) ? wsum[t] : 0;
#pragma unroll
      for (int d = 1; d < 16; d <<= 1) {
        int o = __shfl_up(v, d);
        if (lane >= d) v += o;
      }
      if (t < 16) wsum[t] = v;
    }
    __syncthreads();
    int wpre = (w == 0) ? 0 : wsum[w - 1];
    if (i < n) offsets[i] = cbase + wpre + (sc - x);
    int tot = wsum[15];
    __syncthreads();
    if (t == 0) carry = cbase + tot;
    __syncthreads();
  }
  if (t == 0) offsets[n] = etot;
}

__global__ __launch_bounds__(256) void k_fill(const void* __restrict__ A,
                                              const int* __restrict__ flags,
                                              const int* __restrict__ offsets,
                                              int* cursor, int* __restrict__ csr,
                                              int Eb, int nnode) {
  int e = blockIdx.x * 256 + threadIdx.x;
  if (e >= Eb + nnode) return;
  int s, d;
  if (e < Eb) {
    if (flags[0]) {
      s = (int)((const long long*)A)[e];
      d = (int)((const long long*)A)[(long long)Eb + e];
    } else {
      s = ((const int*)A)[e];
      d = ((const int*)A)[Eb + e];
    }
  } else {
    s = d = e - Eb;
  }
  int slot = atomicAdd(&cursor[d], 1);
  csr[offsets[d] + slot] = s;
}

#define AGG_STEP(IDX, ACC)                                              \
  {                                                                     \
    int idx_ = (IDX);                                                   \
    float cl_ = __shfl(c, idx_);                                        \
    int sr_ = __shfl(sl, idx_);                                         \
    if (idx_ < glim) {                                                  \
      const float4 hv_ = *(const float4*)&h[(size_t)sr_ * 64 + f4 * 4]; \
      ACC.x = fmaf(cl_, hv_.x, ACC.x);                                  \
      ACC.y = fmaf(cl_, hv_.y, ACC.y);                                  \
      ACC.z = fmaf(cl_, hv_.z, ACC.z);                                  \
      ACC.w = fmaf(cl_, hv_.w, ACC.w);                                  \
    }                                                                   \
  }

// wave-per-node aggregate: register alpha (deg<=64 fast path), pass B as
// 4-edge x 16-lane float4 gather with dual accumulators.
template <int DROPOUT>
__global__ __launch_bounds__(256) void k_aggregate(
    const float* __restrict__ h, const float* __restrict__ ssrc,
    const float* __restrict__ sdst, const float* __restrict__ bias,
    const int* __restrict__ offsets, const int* __restrict__ csr,
    float* __restrict__ alphaE, float* __restrict__ out, int n) {
  int wid = (blockIdx.x * 256 + threadIdx.x) >> 6;
  int lane = threadIdx.x & 63;
  if (wid >= n) return;
  int off = offsets[wid];
  int end = offsets[wid + 1];
  int g = end - off;
  float sd = sdst[wid];
  int e4 = lane >> 4, f4 = lane & 15;
  float4 acc0 = {0.f, 0.f, 0.f, 0.f}, acc1 = {0.f, 0.f, 0.f, 0.f};

  if (g <= 64) {
    int sl = 0;
    float v = -1e30f;
    if (lane < g) {
      sl = csr[off + lane];
      float tv = ssrc[sl] + sd;
      v = (tv > 0.f) ? tv : 0.2f * tv;
    }
    float m = v;
#pragma unroll
    for (int d = 32; d; d >>= 1) m = fmaxf(m, __shfl_xor(m, d));
    float ex = (lane < g) ? __expf(v - m) : 0.f;
    float s = ex;
#pragma unroll
    for (int d = 32; d; d >>= 1) s += __shfl_xor(s, d);
    float c = ex * (1.f / s);
    int glim = g;
    for (int cb = 0; cb < g; cb += 8) {
      AGG_STEP(cb + e4, acc0)
      AGG_STEP(cb + 4 + e4, acc1)
    }
  } else {
    float mm = -1e30f, ss = 0.f;
    for (int e = off + lane; e < end; e += 64) {
      int sl2 = csr[e];
      float tv = ssrc[sl2] + sd;
      tv = (tv > 0.f) ? tv : 0.2f * tv;
      alphaE[e] = tv;
      float mn = fmaxf(mm, tv);
      ss = ss * __expf(mm - mn) + __expf(tv - mn);
      mm = mn;
    }
#pragma unroll
    for (int d = 32; d; d >>= 1) {
      float mo = __shfl_xor(mm, d);
      float so = __shfl_xor(ss, d);
      float mn = fmaxf(mm, mo);
      ss = ss * __expf(mm - mn) + so * __expf(mo - mn);
      mm = mn;
    }
    float inv = 1.f / ss;
    for (int base = off; base < end; base += 64) {
      int e = base + lane;
      int cnt = min(64, end - base);
      float c = 0.f;
      int sl = 0;
      if (e < end) {
        c = __expf(alphaE[e] - mm) * inv;
        sl = csr[e];
      }
      int glim = cnt;
      for (int cb = 0; cb < cnt; cb += 8) {
        AGG_STEP(cb + e4, acc0)
        AGG_STEP(cb + 4 + e4, acc1)
      }
    }
  }

  float4 r;
  r.x = acc0.x + acc1.x;
  r.y = acc0.y + acc1.y;
  r.z = acc0.z + acc1.z;
  r.w = acc0.w + acc1.w;
#pragma unroll
  for (int d = 16; d < 64; d <<= 1) {
    r.x += __shfl_xor(r.x, d);
    r.y += __shfl_xor(r.y, d);
    r.z += __shfl_xor(r.z, d);
    r.w += __shfl_xor(r.w, d);
  }

  unsigned long long mask = 0ull;
  if (DROPOUT) {
    unsigned i0 = (unsigned)wid * 64u + (unsigned)lane;
    unsigned o0, o1;
    threefry2_0_42(0u, i0, &o0, &o1);
    unsigned bits = o0 ^ o1;
    float u = __uint_as_float((bits >> 9) | 0x3f800000u) - 1.0f;
    mask = __ballot(u < 0.7f);
  }

  if (lane < 16) {
    const float4 b4 = *(const float4*)&bias[lane * 4];
    r.x = fmaxf(r.x + b4.x, 0.f);
    r.y = fmaxf(r.y + b4.y, 0.f);
    r.z = fmaxf(r.z + b4.z, 0.f);
    r.w = fmaxf(r.w + b4.w, 0.f);
    if (DROPOUT) {
      r.x = ((mask >> (lane * 4 + 0)) & 1ull) ? r.x / 0.7f : 0.f;
      r.y = ((mask >> (lane * 4 + 1)) & 1ull) ? r.y / 0.7f : 0.f;
      r.z = ((mask >> (lane * 4 + 2)) & 1ull) ? r.z / 0.7f : 0.f;
      r.w = ((mask >> (lane * 4 + 3)) & 1ull) ? r.w / 0.7f : 0.f;
    }
    *(float4*)&out[(size_t)wid * 64 + lane * 4] = r;
  }
}

extern "C" void kernel_launch(void* const* d_in, const int* in_sizes, int n_in,
                              void* d_out, int out_size, void* d_ws, size_t ws_size,
                              hipStream_t stream) {
  const void* E = d_in[0];
  const void* A = d_in[1];
  const void* W1 = d_in[2];
  const void* as1 = d_in[3];
  const void* ad1 = d_in[4];
  const void* b1 = d_in[5];
  const void* W2 = d_in[6];
  const void* as2 = d_in[7];
  const void* ad2 = d_in[8];
  const void* b2 = d_in[9];
  float* out = (float*)d_out;

  const int N = in_sizes[0] / 64;   // 50000
  const int Eb = in_sizes[1] / 2;   // 800000
  const int Etot = Eb + N;          // 850000
  const int total = N * 64;

  float* ws = (float*)d_ws;
  float* h = ws;                          // total
  float* x1 = h + (size_t)total;          // total
  float* ssrc = x1 + (size_t)total;       // N
  float* sdst = ssrc + N;                 // N
  float* alphaE = sdst + N;               // Etot
  float* smallc = alphaE + Etot;          // 8576
  int* deg = (int*)(smallc + 8576);       // N
  int* offsets = deg + N;                 // N+1
  int* cursor = offsets + (N + 1);        // N
  int* flags = cursor + N;                // 2
  int* csr = flags + 2;                   // Etot

  float* W1c = smallc;
  float* as1c = smallc + 4096;
  float* ad1c = smallc + 4160;
  float* b1c = smallc + 4224;
  float* W2c = smallc + 4288;
  float* as2c = smallc + 8384;
  float* ad2c = smallc + 8448;
  float* b2c = smallc + 8512;

  const int gPrep = (N + 255) / 256;            // 196
  const int nCountBlocks = (Eb + 255) / 256;    // 3125
  const int gTile = (N + 63) / 64;              // 782 GEMM tiles
  const int gAgg = (N + 3) / 4;                 // 12500 (wave per node)
  const int gFill = (Etot + 255) / 256;

  k_prep<<<gPrep, 256, 0, stream>>>(A, E, N, W1, as1, ad1, b1, W2, as2, ad2,
                                    b2, smallc, deg, cursor, flags);
  k_count_gemm<<<nCountBlocks + gTile, 256, 0, stream>>>(
      A, flags, Eb, deg, E, 1, W1c, as1c, ad1c, h, ssrc, sdst, N, nCountBlocks);
  k_scan_one<<<1, 1024, 0, stream>>>(deg, offsets, N, Etot);
  k_fill<<<gFill, 256, 0, stream>>>(A, flags, offsets, cursor, csr, Eb, N);
  k_aggregate<1><<<gAgg, 256, 0, stream>>>(h, ssrc, sdst, b1c, offsets, csr,
                                           alphaE, x1, N);
  k_count_gemm<<<gTile, 256, 0, stream>>>(A, flags, Eb, deg, x1, 0, W2c, as2c,
                                          ad2c, h, ssrc, sdst, N, 0);
  k_aggregate<0><<<gAgg, 256, 0, stream>>>(h, ssrc, sdst, b2c, offsets, csr,
                                           alphaE, out, N);
}